// Round 1
// 392.623 us; speedup vs baseline: 1.0307x; 1.0307x over previous
//
#include <hip/hip_runtime.h>
#include <math.h>

#define TOKENS 16384
#define HIDDEN 4096
#define NEXP   64
#define TOKB   32                // tokens per block (2 MFMA row-frags per wave)
#define WAVES  4
#define KSL    (HIDDEN / WAVES)  // 1024 k per wave (waves split K, not tokens)
#define NCH    (KSL / 32)        // 32 mfma k-chunks per wave

typedef _Float16 half8 __attribute__((ext_vector_type(8)));
typedef float    f32x4 __attribute__((ext_vector_type(4)));

// Pre-pack W [64][4096] fp32 -> Wh/Wl fp16 in MFMA B-layout [kblock][expert][32k]
__global__ void w_prep(const float* __restrict__ W,
                       _Float16* __restrict__ Wh, _Float16* __restrict__ Wl) {
    int idx = blockIdx.x * blockDim.x + threadIdx.x;   // = e*4096 + k
    int e = idx >> 12;
    int k = idx & 4095;
    float v = W[idx];
    _Float16 h = (_Float16)v;                // RTN, 11-bit mantissa
    _Float16 l = (_Float16)(v - (float)h);   // residual
    size_t dst = (((size_t)(k >> 5) * NEXP) + e) * 32 + (k & 31);
    Wh[dst] = h;
    Wl[dst] = l;
}

__device__ __forceinline__ void split8(const float4& p0, const float4& p1,
                                       half8& h, half8& l) {
    const float v[8] = {p0.x, p0.y, p0.z, p0.w, p1.x, p1.y, p1.z, p1.w};
    #pragma unroll
    for (int j = 0; j < 8; ++j) {
        _Float16 hi = (_Float16)v[j];
        h[j] = hi;
        l[j] = (_Float16)(v[j] - (float)hi);
    }
}

// Fused: logits (fp16 hi/lo split MFMA, 3 products) + cross-wave K-reduce in LDS
// + top-2 + softmax, one pass over x. No partial buffer, no second kernel.
__global__ __launch_bounds__(256, 2) void router_fused(
    const float* __restrict__ x, const _Float16* __restrict__ Wh,
    const _Float16* __restrict__ Wl, float* __restrict__ out)
{
    // [wave][expert][token(+pad)] — stride 36 floats: ds_write_b128 start banks
    // (e*36 + tok)/1 %32 = (e*4 + quad*4)%32 -> 2-way max (free).
    __shared__ float lds[WAVES][NEXP][36];

    const int tid  = threadIdx.x;
    const int lane = tid & 63;
    const int wv   = tid >> 6;       // 0..3 : K-slice owner
    const int e16  = lane & 15;
    const int quad = lane >> 4;

    const int tok0 = blockIdx.x * TOKB;
    const int kb0  = wv * NCH;       // this wave's first 32k-block

    f32x4 accA[4], accB[4];
    #pragma unroll
    for (int n = 0; n < 4; ++n) {
        accA[n] = (f32x4){0.f, 0.f, 0.f, 0.f};
        accB[n] = (f32x4){0.f, 0.f, 0.f, 0.f};
    }

    // A: lane holds x[row][k]; frag A rows tok0+e16, frag B rows +16
    const float* xpA = x + (size_t)(tok0 + e16) * HIDDEN + wv * KSL + quad * 8;
    const float* xpB = xpA + (size_t)16 * HIDDEN;

    float4 pA0 = *(const float4*)(xpA),     pA1 = *(const float4*)(xpA + 4);
    float4 pB0 = *(const float4*)(xpB),     pB1 = *(const float4*)(xpB + 4);

    for (int c = 0; c < NCH; ++c) {
        // B frags: [kblock][expert][32k] -> wave reads contiguous 1KB runs (L2)
        const size_t bo = (((size_t)(kb0 + c) * NEXP) + e16) * 32 + quad * 8;
        half8 bh[4], bl[4];
        #pragma unroll
        for (int n = 0; n < 4; ++n) {
            bh[n] = *reinterpret_cast<const half8*>(Wh + bo + (size_t)n * 16 * 32);
            bl[n] = *reinterpret_cast<const half8*>(Wl + bo + (size_t)n * 16 * 32);
        }

        // split current A regs, then immediately re-use them as prefetch regs
        half8 ahA, alA, ahB, alB;
        split8(pA0, pA1, ahA, alA);
        split8(pB0, pB1, ahB, alB);
        if (c + 1 < NCH) {
            pA0 = *(const float4*)(xpA + (c + 1) * 32);
            pA1 = *(const float4*)(xpA + (c + 1) * 32 + 4);
            pB0 = *(const float4*)(xpB + (c + 1) * 32);
            pB1 = *(const float4*)(xpB + (c + 1) * 32 + 4);
        }

        // 8 chains x 3 dependent MFMAs; >=7 independent ops between links
        #pragma unroll
        for (int n = 0; n < 4; ++n)
            accA[n] = __builtin_amdgcn_mfma_f32_16x16x32_f16(alA, bh[n], accA[n], 0, 0, 0);
        #pragma unroll
        for (int n = 0; n < 4; ++n)
            accB[n] = __builtin_amdgcn_mfma_f32_16x16x32_f16(alB, bh[n], accB[n], 0, 0, 0);
        #pragma unroll
        for (int n = 0; n < 4; ++n)
            accA[n] = __builtin_amdgcn_mfma_f32_16x16x32_f16(ahA, bl[n], accA[n], 0, 0, 0);
        #pragma unroll
        for (int n = 0; n < 4; ++n)
            accB[n] = __builtin_amdgcn_mfma_f32_16x16x32_f16(ahB, bl[n], accB[n], 0, 0, 0);
        #pragma unroll
        for (int n = 0; n < 4; ++n)
            accA[n] = __builtin_amdgcn_mfma_f32_16x16x32_f16(ahA, bh[n], accA[n], 0, 0, 0);
        #pragma unroll
        for (int n = 0; n < 4; ++n)
            accB[n] = __builtin_amdgcn_mfma_f32_16x16x32_f16(ahB, bh[n], accB[n], 0, 0, 0);
    }

    // D layout: col(expert) = n*16+e16, row(token) = quad*4+r.
    // Store per-wave partials: lds[wv][expert][token], b128 per frag.
    #pragma unroll
    for (int n = 0; n < 4; ++n) {
        *(f32x4*)&lds[wv][n * 16 + e16][quad * 4]      = accA[n];
        *(f32x4*)&lds[wv][n * 16 + e16][16 + quad * 4] = accB[n];
    }
    __syncthreads();

    // Cross-wave K-reduce: each thread owns an exclusive (e, 8-token) strip,
    // so read-then-overwrite of lds[0] needs no extra barrier.
    {
        const int e = tid >> 2;
        const int q = tid & 3;
        f32x4 s0 = (f32x4){0.f, 0.f, 0.f, 0.f};
        f32x4 s1 = (f32x4){0.f, 0.f, 0.f, 0.f};
        #pragma unroll
        for (int w = 0; w < WAVES; ++w) {   // fixed order: deterministic
            s0 += *(const f32x4*)&lds[w][e][q * 8];
            s1 += *(const f32x4*)&lds[w][e][q * 8 + 4];
        }
        *(f32x4*)&lds[0][e][q * 8]     = s0;
        *(f32x4*)&lds[0][e][q * 8 + 4] = s1;
    }
    __syncthreads();

    // Top-2 + softmax: lane t scans 64 experts. Bank (e*4+t)%32 distinct per
    // lane -> conflict-free column reads.
    if (tid < TOKB) {
        float v1 = -INFINITY, v2 = -INFINITY;
        int i1 = 0, i2 = 0;
        #pragma unroll 8
        for (int e = 0; e < NEXP; ++e) {
            float v = lds[0][e][tid];
            if (v > v1)      { v2 = v1; i2 = i1; v1 = v; i1 = e; }
            else if (v > v2) { v2 = v;  i2 = e; }
        }
        float e2 = expf(v2 - v1);
        float d  = 1.f / (1.f + e2);
        int t = tok0 + tid;
        out[t * 2 + 0] = d;
        out[t * 2 + 1] = e2 * d;
        out[2 * TOKENS + t * 2 + 0] = (float)i1;
        out[2 * TOKENS + t * 2 + 1] = (float)i2;
    }
}

extern "C" void kernel_launch(void* const* d_in, const int* in_sizes, int n_in,
                              void* d_out, int out_size, void* d_ws, size_t ws_size,
                              hipStream_t stream) {
    const float* x = (const float*)d_in[0];     // [16384, 4096]
    const float* W = (const float*)d_in[1];     // [64, 4096]
    float* out = (float*)d_out;

    _Float16* Wh = (_Float16*)d_ws;                       // 512 KB
    _Float16* Wl = Wh + (size_t)NEXP * HIDDEN;            // 512 KB

    w_prep<<<(NEXP * HIDDEN) / 256, 256, 0, stream>>>(W, Wh, Wl);
    router_fused<<<TOKENS / TOKB, 256, 0, stream>>>(x, Wh, Wl, out);
}

// Round 3
// 391.177 us; speedup vs baseline: 1.0346x; 1.0037x over previous
//
#include <hip/hip_runtime.h>
#include <math.h>

#define TOKENS 16384
#define HIDDEN 4096
#define NEXP   64
#define TOKB   32                // tokens per block (2 MFMA row-frags per wave)
#define WAVES  4
#define KSL    (HIDDEN / WAVES)  // 1024 k per wave (waves split K, not tokens)
#define NCH    (KSL / 32)        // 32 mfma k-chunks per wave

typedef _Float16 half8 __attribute__((ext_vector_type(8)));
typedef float    f32x4 __attribute__((ext_vector_type(4)));

// fp32 -> fp16 hi + fp16 residual (RTN). Same numerics as the old w_prep path.
__device__ __forceinline__ void split8(const float4& p0, const float4& p1,
                                       half8& h, half8& l) {
    const float v[8] = {p0.x, p0.y, p0.z, p0.w, p1.x, p1.y, p1.z, p1.w};
    #pragma unroll
    for (int j = 0; j < 8; ++j) {
        _Float16 hi = (_Float16)v[j];
        h[j] = hi;
        l[j] = (_Float16)(v[j] - (float)hi);
    }
}

// Single fused kernel, ZERO workspace use:
//  - logits via fp16 hi/lo split MFMA (3 products, l*l dropped)
//  - W converted fp32->hi/lo on the fly in registers (W is 1MB, L2-resident;
//    fp32 read bytes == old Wh+Wl read bytes, so no extra traffic)
//  - cross-wave K-reduce in LDS + top-2 + softmax epilogue
__global__ __launch_bounds__(256, 2) void router_fused(
    const float* __restrict__ x, const float* __restrict__ W,
    float* __restrict__ out)
{
    // [wave][expert][token(+pad)] — stride 36 floats keeps b128 stores ~2-way
    __shared__ float lds[WAVES][NEXP][36];

    const int tid  = threadIdx.x;
    const int lane = tid & 63;
    const int wv   = tid >> 6;       // 0..3 : K-slice owner
    const int e16  = lane & 15;
    const int quad = lane >> 4;
    const int tok0 = blockIdx.x * TOKB;

    f32x4 accA[4], accB[4];
    #pragma unroll
    for (int n = 0; n < 4; ++n) {
        accA[n] = (f32x4){0.f, 0.f, 0.f, 0.f};
        accB[n] = (f32x4){0.f, 0.f, 0.f, 0.f};
    }

    // A: lane holds x[row][k]; frag A rows tok0+e16, frag B rows +16
    const float* xpA = x + (size_t)(tok0 + e16) * HIDDEN + wv * KSL + quad * 8;
    const float* xpB = xpA + (size_t)16 * HIDDEN;
    // B: lane (e16,quad) reads W[n*16+e16][k0 + c*32 + quad*8 .. +8]
    const float* wp  = W + (size_t)e16 * HIDDEN + wv * KSL + quad * 8;

    // x prefetch: 2 chunks deep, two NAMED register sets (static indexing only)
    float4 a00 = *(const float4*)(xpA),      a01 = *(const float4*)(xpA + 4);
    float4 b00 = *(const float4*)(xpB),      b01 = *(const float4*)(xpB + 4);
    float4 a10 = *(const float4*)(xpA + 32), a11 = *(const float4*)(xpA + 36);
    float4 b10 = *(const float4*)(xpB + 32), b11 = *(const float4*)(xpB + 36);

    // W prefetch: 1 chunk deep (L2-hit latency only)
    float4 w0[4], w1[4];
    #pragma unroll
    for (int n = 0; n < 4; ++n) {
        w0[n] = *(const float4*)(wp + (size_t)n * 16 * HIDDEN);
        w1[n] = *(const float4*)(wp + (size_t)n * 16 * HIDDEN + 4);
    }

#define CHUNK_BODY(c, A0, A1, B0, B1)                                          \
    {                                                                          \
        half8 bh[4], bl[4];                                                    \
        _Pragma("unroll")                                                      \
        for (int n = 0; n < 4; ++n) split8(w0[n], w1[n], bh[n], bl[n]);        \
        if ((c) + 1 < NCH) {                                                   \
            _Pragma("unroll")                                                  \
            for (int n = 0; n < 4; ++n) {                                      \
                w0[n] = *(const float4*)(wp + (size_t)n * 16 * HIDDEN          \
                                             + ((c) + 1) * 32);                \
                w1[n] = *(const float4*)(wp + (size_t)n * 16 * HIDDEN          \
                                             + ((c) + 1) * 32 + 4);            \
            }                                                                  \
        }                                                                      \
        half8 ahA, alA, ahB, alB;                                              \
        split8(A0, A1, ahA, alA);                                              \
        split8(B0, B1, ahB, alB);                                              \
        if ((c) + 2 < NCH) {                                                   \
            A0 = *(const float4*)(xpA + ((c) + 2) * 32);                       \
            A1 = *(const float4*)(xpA + ((c) + 2) * 32 + 4);                   \
            B0 = *(const float4*)(xpB + ((c) + 2) * 32);                       \
            B1 = *(const float4*)(xpB + ((c) + 2) * 32 + 4);                   \
        }                                                                      \
        _Pragma("unroll")                                                      \
        for (int n = 0; n < 4; ++n)                                            \
            accA[n] = __builtin_amdgcn_mfma_f32_16x16x32_f16(alA, bh[n],       \
                                                             accA[n], 0, 0, 0);\
        _Pragma("unroll")                                                      \
        for (int n = 0; n < 4; ++n)                                            \
            accB[n] = __builtin_amdgcn_mfma_f32_16x16x32_f16(alB, bh[n],       \
                                                             accB[n], 0, 0, 0);\
        _Pragma("unroll")                                                      \
        for (int n = 0; n < 4; ++n)                                            \
            accA[n] = __builtin_amdgcn_mfma_f32_16x16x32_f16(ahA, bl[n],       \
                                                             accA[n], 0, 0, 0);\
        _Pragma("unroll")                                                      \
        for (int n = 0; n < 4; ++n)                                            \
            accB[n] = __builtin_amdgcn_mfma_f32_16x16x32_f16(ahB, bl[n],       \
                                                             accB[n], 0, 0, 0);\
        _Pragma("unroll")                                                      \
        for (int n = 0; n < 4; ++n)                                            \
            accA[n] = __builtin_amdgcn_mfma_f32_16x16x32_f16(ahA, bh[n],       \
                                                             accA[n], 0, 0, 0);\
        _Pragma("unroll")                                                      \
        for (int n = 0; n < 4; ++n)                                            \
            accB[n] = __builtin_amdgcn_mfma_f32_16x16x32_f16(ahB, bh[n],       \
                                                             accB[n], 0, 0, 0);\
    }

    for (int c = 0; c < NCH; c += 2) {
        CHUNK_BODY(c,     a00, a01, b00, b01);
        CHUNK_BODY(c + 1, a10, a11, b10, b11);
    }
#undef CHUNK_BODY

    // D layout: col(expert) = n*16+e16, row(token) = quad*4+r.
    // Store per-wave partials: lds[wv][expert][token], b128 per frag.
    #pragma unroll
    for (int n = 0; n < 4; ++n) {
        *(f32x4*)&lds[wv][n * 16 + e16][quad * 4]      = accA[n];
        *(f32x4*)&lds[wv][n * 16 + e16][16 + quad * 4] = accB[n];
    }
    __syncthreads();

    // Cross-wave K-reduce: each thread owns an exclusive (e, 8-token) strip,
    // so read-then-overwrite of lds[0] needs no extra barrier.
    {
        const int e = tid >> 2;
        const int q = tid & 3;
        f32x4 s0 = (f32x4){0.f, 0.f, 0.f, 0.f};
        f32x4 s1 = (f32x4){0.f, 0.f, 0.f, 0.f};
        #pragma unroll
        for (int w = 0; w < WAVES; ++w) {   // fixed order: deterministic
            s0 += *(const f32x4*)&lds[w][e][q * 8];
            s1 += *(const f32x4*)&lds[w][e][q * 8 + 4];
        }
        *(f32x4*)&lds[0][e][q * 8]     = s0;
        *(f32x4*)&lds[0][e][q * 8 + 4] = s1;
    }
    __syncthreads();

    // Top-2 + softmax: lane t scans 64 experts, conflict-free column reads.
    if (tid < TOKB) {
        float v1 = -INFINITY, v2 = -INFINITY;
        int i1 = 0, i2 = 0;
        #pragma unroll 8
        for (int e = 0; e < NEXP; ++e) {
            float v = lds[0][e][tid];
            if (v > v1)      { v2 = v1; i2 = i1; v1 = v; i1 = e; }
            else if (v > v2) { v2 = v;  i2 = e; }
        }
        float e2 = expf(v2 - v1);
        float d  = 1.f / (1.f + e2);
        int t = tok0 + tid;
        out[t * 2 + 0] = d;
        out[t * 2 + 1] = e2 * d;
        out[2 * TOKENS + t * 2 + 0] = (float)i1;
        out[2 * TOKENS + t * 2 + 1] = (float)i2;
    }
}

extern "C" void kernel_launch(void* const* d_in, const int* in_sizes, int n_in,
                              void* d_out, int out_size, void* d_ws, size_t ws_size,
                              hipStream_t stream) {
    const float* x = (const float*)d_in[0];     // [16384, 4096]
    const float* W = (const float*)d_in[1];     // [64, 4096]
    float* out = (float*)d_out;
    (void)d_ws; (void)ws_size;                  // workspace deliberately unused

    router_fused<<<TOKENS / TOKB, 256, 0, stream>>>(x, W, out);
}